// Round 12
// baseline (251.837 us; speedup 1.0000x reference)
//
#include <hip/hip_runtime.h>
#include <hip/hip_fp16.h>

// GCN 2-layer -- r24c: resubmit of r24 (round-10 "container failed twice"
// and round-11 "GPUAcquisitionTimeout" were both infra -- the r11 error is
// explicit broker capacity; source audit found no defect).
// deg via atomics in k_part; GEMM1 (prescaled, r15 form) moved under the
// latency-bound sort launch; Hh prescale pass eliminated.
// Ledger (keep):
//  r16 (374us): scatter-to-final-slot = 120MB random 64B RMW @0.8TB/s.
//      Random WRITES are the weak axis. Never undo the two-stage sort.
//  r17 (231us): fat k_part blocks -> latency-starved.
//  r18b (206us): GEMM1 under RMW-bound k_part: zero overlap.
//  r19 (200.5us): per-block LDS sort -> coalesced runs+seg. GEMM1 overlap
//      real. Per-edge dinv in fused48 costs ~7us vs prescaled.
//  r20 (202.4us): LDS-staged per-edge dinv WORSE; segt ~= wash.
//  r21 (198.8us): Hh prescaled in bsort2; fused48 at 44.7us/101.7MB floor.
//  r22 (653us): mega-kernel + grid barriers CATASTROPHIC (Occ 37% -> 768
//      slots < 782 blocks, spin storms). RULE: sync at kernel bounds only.
//  r23 (193.6us): r21 minus segt (column seg reads beat transpose+launch).
//      fused48 43.5us @ 2.56TB/s = compulsory floor.
// r24 mechanism: dinv needs only deg = histogram(dst) -- NOT the sort.
//  (1) k_part: partition + 1.6M fire-and-forget atomicAdd into deg[100k]
//      (400KB, L2-resident; NOT the r16 mode -- no line-allocating stores).
//  (2) k_bsortgemm merged launch: sort branch sheds the 19.2MB Hh prescale
//      (GEMM writes prescaled directly, reading deg from launch 1); GEMM's
//      ~10us hides under the sort's latency-bound random gather.
//  fused48/k_agg byte-identical r15-proven forms.
// out = GCNConv(relu(GCNConv(x,W1,b1)), W2, b2); N=100k, E=1.6M, 64->48->32.

#define NN 100000
#define NE 1600000
#define NPB 128                         // nodes per bucket
#define NBUCK ((NN + NPB - 1) / NPB)    // 782
#define PBITS 17                        // src fits in 17 bits
#define PMASK ((1 << PBITS) - 1)
#define CHB 3                           // log2 src chunks
#define CHS 14                          // chunk = src >> 14
#define NKEY (NPB << CHB)               // 1024 sort keys per bucket
#define CAP 4096                        // static slots per bucket (45-sigma)
#define UN 8                            // agg edge-loop unroll (masked batches)
#define PART_B 512
#define EPT 8                           // edges per thread
#define RUNW (PART_B * EPT)             // 4096 edges per partition block run
#define PART_G ((NE + RUNW - 1) / RUNW) // 391
#define GB NBUCK                        // fused48 grid (782)
#define GEMM2_G ((NN + 127) / 128)      // 782 gemm blocks @256thr/128rows

struct alignas(8)  half4 { __half2 lo, hi; };
struct alignas(16) half8 { __half2 a, b, c, d; };

// Partition only (r15-proven geometry 391x512xEPT8) + deg histogram.
__global__ __launch_bounds__(512) void
k_part(const int* __restrict__ src, const int* __restrict__ dst,
       int* __restrict__ runs, unsigned int* __restrict__ seg,
       int* __restrict__ deg) {
    __shared__ int h[NBUCK];
    __shared__ int tsum[512];
    __shared__ int stage[RUNW];       // 16 KB
    int tid = threadIdx.x;

    for (int i = tid; i < NBUCK; i += PART_B) h[i] = 0;
    __syncthreads();
    int ebase = blockIdx.x * RUNW;
    int pw[EPT], pb[EPT];
#pragma unroll
    for (int k = 0; k < EPT; ++k) {
        int e = ebase + k * PART_B + tid;
        if (e < NE) {
            int d = dst[e];
            pb[k] = d >> 7;
            pw[k] = src[e] | ((d & (NPB - 1)) << PBITS);
            atomicAdd(&h[pb[k]], 1);
            atomicAdd(&deg[d], 1);           // fire-and-forget, L2-resident
        } else pb[k] = -1;
    }
    __syncthreads();
    // scan 782 counters, 2 per thread (tid < 391)
    int c0 = 0, c1 = 0;
    if (tid < NBUCK / 2) { c0 = h[2 * tid]; c1 = h[2 * tid + 1]; }
    int loc = c0 + c1;
    tsum[tid] = (tid < NBUCK / 2) ? loc : 0;
    __syncthreads();
    for (int off = 1; off < 512; off <<= 1) {
        int v = (tid >= off) ? tsum[tid - off] : 0;
        __syncthreads();
        tsum[tid] += v;
        __syncthreads();
    }
    if (tid < NBUCK / 2) {
        int base = tsum[tid] - loc;
        seg[(size_t)blockIdx.x * NBUCK + 2 * tid]     = ((unsigned)base << 9) | (unsigned)c0;
        seg[(size_t)blockIdx.x * NBUCK + 2 * tid + 1] = ((unsigned)(base + c0) << 9) | (unsigned)c1;
        h[2 * tid]     = base;
        h[2 * tid + 1] = base + c0;
    }
    __syncthreads();
#pragma unroll
    for (int k = 0; k < EPT; ++k) {
        if (pb[k] >= 0) {
            int r = atomicAdd(&h[pb[k]], 1);
            stage[r] = pw[k];
        }
    }
    __syncthreads();
#pragma unroll
    for (int k = 0; k < EPT; ++k)
        runs[(size_t)blockIdx.x * RUNW + k * PART_B + tid] = stage[k * PART_B + tid];
}

struct SortLds {
    int stage[CAP];      // 16384 B
    int cnt[NKEY];       // 4096 B
    int tsum[256];       // 1024 B
};
struct GemmLds { float w[64 * 48]; };   // 12288 B
union BGLds { SortLds s; GemmLds g; };  // 21504 B -> ~7 blocks/CU

// Merged launch, 256 threads, NBUCK + GEMM2_G blocks.
// Blocks [0,NBUCK): per-bucket sort (r23 form, PRESCALE REMOVED): gather
//   bucket b's 391 segments (seg column-major), counting-sort to srcsort,
//   emit rowinfo + dinv. No Hh access.
// Blocks [NBUCK,..): GEMM1 Hh[row] = half((X@W1) * rsqrtf(deg[row]+1)) --
//   the r15-proven 128-row/256-thr register tile, prescaled epilogue.
// Independent given {runs, seg, deg} from launch 1 -> true overlap.
__global__ __launch_bounds__(256) void
k_bsortgemm(const int* __restrict__ runs, const unsigned int* __restrict__ seg,
            int* __restrict__ srcsort, unsigned int* __restrict__ rowinfo,
            float* __restrict__ dinv, const int* __restrict__ deg,
            const float* __restrict__ X, const float* __restrict__ W1,
            __half* __restrict__ Hh) {
    __shared__ BGLds U;
    int tid = threadIdx.x;

    if (blockIdx.x < NBUCK) {
        int b = blockIdx.x;
        // gather segments: thread t handles partition blocks t and t+256
        unsigned int s0 = (tid < PART_G) ? seg[(size_t)tid * NBUCK + b] : 0u;
        unsigned int s1 = (tid + 256 < PART_G) ? seg[(size_t)(tid + 256) * NBUCK + b] : 0u;
        int l0 = (int)(s0 & 511u), l1 = (int)(s1 & 511u);
        int mylen = l0 + l1;
        U.s.tsum[tid] = mylen;
        __syncthreads();
        for (int off = 1; off < 256; off <<= 1) {
            int v = (tid >= off) ? U.s.tsum[tid - off] : 0;
            __syncthreads();
            U.s.tsum[tid] += v;
            __syncthreads();
        }
        int wbase = U.s.tsum[tid] - mylen;
        int sz = U.s.tsum[255];
        {
            const int* p = runs + (size_t)tid * RUNW + (s0 >> 9);
            for (int i = 0; i < l0; ++i) U.s.stage[wbase + i] = p[i];
            p = runs + (size_t)(tid + 256) * RUNW + (s1 >> 9);
            for (int i = 0; i < l1; ++i) U.s.stage[wbase + l0 + i] = p[i];
        }
        for (int i = tid; i < NKEY; i += 256) U.s.cnt[i] = 0;
        __syncthreads();

        for (int i = tid; i < sz; i += 256) {
            int w = U.s.stage[i];
            int key = ((w >> PBITS) << CHB) | ((w & PMASK) >> CHS);
            atomicAdd(&U.s.cnt[key], 1);
        }
        __syncthreads();
        int k0 = tid * 4;
        int c0 = U.s.cnt[k0], c1 = U.s.cnt[k0 + 1];
        int c2 = U.s.cnt[k0 + 2], c3 = U.s.cnt[k0 + 3];
        int loc = c0 + c1 + c2 + c3;
        U.s.tsum[tid] = loc;
        __syncthreads();
        for (int off = 1; off < 256; off <<= 1) {
            int v = (tid >= off) ? U.s.tsum[tid - off] : 0;
            __syncthreads();
            U.s.tsum[tid] += v;
            __syncthreads();
        }
        int base = U.s.tsum[tid] - loc;
        U.s.cnt[k0]     = base;
        U.s.cnt[k0 + 1] = base + c0;
        U.s.cnt[k0 + 2] = base + c0 + c1;
        U.s.cnt[k0 + 3] = base + c0 + c1 + c2;
        __syncthreads();
        int e0 = b * CAP;
        if (tid < NPB) {
            int node = b * NPB + tid;
            int rs = U.s.cnt[tid << CHB];
            int re = (tid == NPB - 1) ? sz : U.s.cnt[(tid + 1) << CHB];
            if (node < NN) {
                rowinfo[node] = ((unsigned int)(e0 + rs) << 10) | (unsigned int)(re - rs);
                dinv[node] = rsqrtf((float)(re - rs + 1));   // +1 self-loop
            }
        }
        __syncthreads();
        for (int i = tid; i < sz; i += 256) {
            int w = U.s.stage[i];
            int key = ((w >> PBITS) << CHB) | ((w & PMASK) >> CHS);
            int p = atomicAdd(&U.s.cnt[key], 1);
            srcsort[e0 + p] = w & PMASK;
        }
        return;
    }

    // ---- GEMM1 (r15-proven: 128 rows/block @256thr, 2x12/thread, prescaled) ----
    constexpr int NC = 48, CPT = 12, CG = 4, KF4 = 16;
    int R0 = (blockIdx.x - NBUCK) * 128;
    for (int i = tid; i < 64 * 48; i += 256) U.g.w[i] = W1[i];
    __syncthreads();

    int tc = tid % CG, tr = tid / CG;          // tr in [0,64)
    int r0 = R0 + 2 * tr, r1 = r0 + 1;
    int c0 = tc * CPT;
    bool ok0 = r0 < NN, ok1 = r1 < NN;
    const float4* X4 = (const float4*)X;
    const float4 z4 = make_float4(0.f, 0.f, 0.f, 0.f);

    float acc[2][CPT];
#pragma unroll
    for (int rr = 0; rr < 2; ++rr)
#pragma unroll
        for (int j = 0; j < CPT; ++j) acc[rr][j] = 0.f;

#pragma unroll 2
    for (int k4 = 0; k4 < KF4; ++k4) {
        float4 xa = ok0 ? X4[(size_t)r0 * KF4 + k4] : z4;
        float4 xb = ok1 ? X4[(size_t)r1 * KF4 + k4] : z4;
        float ar[4] = {xa.x, xa.y, xa.z, xa.w};
        float br[4] = {xb.x, xb.y, xb.z, xb.w};
#pragma unroll
        for (int j = 0; j < 4; ++j) {
            float va = ar[j], vb = br[j];
#pragma unroll
            for (int q = 0; q < CPT / 4; ++q) {
                float4 wv = *(const float4*)&U.g.w[(4 * k4 + j) * NC + c0 + 4 * q];
                acc[0][q*4+0] = fmaf(va, wv.x, acc[0][q*4+0]);
                acc[0][q*4+1] = fmaf(va, wv.y, acc[0][q*4+1]);
                acc[0][q*4+2] = fmaf(va, wv.z, acc[0][q*4+2]);
                acc[0][q*4+3] = fmaf(va, wv.w, acc[0][q*4+3]);
                acc[1][q*4+0] = fmaf(vb, wv.x, acc[1][q*4+0]);
                acc[1][q*4+1] = fmaf(vb, wv.y, acc[1][q*4+1]);
                acc[1][q*4+2] = fmaf(vb, wv.z, acc[1][q*4+2]);
                acc[1][q*4+3] = fmaf(vb, wv.w, acc[1][q*4+3]);
            }
        }
    }
#pragma unroll
    for (int rr = 0; rr < 2; ++rr) {
        int gr = r0 + rr;
        if (gr >= NN) continue;
        float d = rsqrtf((float)deg[gr] + 1.0f);   // prescale from deg hist
#pragma unroll
        for (int q = 0; q < CPT / 4; ++q) {
            __half2 p0 = __floats2half2_rn(acc[rr][q*4+0] * d, acc[rr][q*4+1] * d);
            __half2 p1 = __floats2half2_rn(acc[rr][q*4+2] * d, acc[rr][q*4+3] * d);
            half4 hv; hv.lo = p0; hv.hi = p1;
            *(half4*)(Hh + (size_t)gr * NC + c0 + 4 * q) = hv;
        }
    }
}

// Fused layer-1 aggregation + relu/b1 + GEMM2 + dinv. 128-row tile, 256 thr.
// EXACT r15 proven form: Hh is prescaled (by GEMM1), mask = 1.0.
__global__ __launch_bounds__(256) void
k_fused48(const __half* __restrict__ Hh, const unsigned int* __restrict__ rowinfo,
          const int* __restrict__ srcsort, const float* __restrict__ dinv,
          const float* __restrict__ b1, const float* __restrict__ W2,
          __half* __restrict__ Hh2) {
    constexpr int ROWS = 128, XS = 49;
    __shared__ float Xs[ROWS * XS];      // 25088 B
    __shared__ float w2[48 * 32];        // 6144 B
    __shared__ float bb[48];
    int tid = threadIdx.x;
    int R0 = blockIdx.x * ROWS;
    for (int i = tid; i < 48 * 32; i += 256) w2[i] = W2[i];
    if (tid < 48) bb[tid] = b1[tid];
    __syncthreads();

    // ---- phase 1: aggregate into Xs (3 (row,chunk) items per thread) ----
    for (int t = tid; t < ROWS * 6; t += 256) {
        int lr = t / 6, q = t - lr * 6;
        int r = R0 + lr;
        if (r >= NN) continue;
        half8 sv = *(const half8*)(Hh + (size_t)r * 48 + 8 * q);   // self-loop
        float2 f0 = __half22float2(sv.a), f1 = __half22float2(sv.b);
        float2 f2 = __half22float2(sv.c), f3 = __half22float2(sv.d);
        float a0 = f0.x, a1 = f0.y, a2 = f1.x, a3 = f1.y;
        float a4 = f2.x, a5 = f2.y, a6 = f3.x, a7 = f3.y;
        unsigned int rp = rowinfo[r];
        int e0 = rp >> 10, e1 = e0 + (int)(rp & 1023);
        for (int e = e0; e < e1; e += UN) {
            int ss[UN]; float ms[UN];
#pragma unroll
            for (int u = 0; u < UN; ++u) {
                int ee = e + u;
                bool ok = ee < e1;
                ss[u] = srcsort[ok ? ee : e0];
                ms[u] = ok ? 1.f : 0.f;
            }
            half8 vv[UN];
#pragma unroll
            for (int u = 0; u < UN; ++u)
                vv[u] = *(const half8*)(Hh + (size_t)ss[u] * 48 + 8 * q);
#pragma unroll
            for (int u = 0; u < UN; ++u) {
                float2 g0 = __half22float2(vv[u].a), g1 = __half22float2(vv[u].b);
                float2 g2 = __half22float2(vv[u].c), g3 = __half22float2(vv[u].d);
                float m = ms[u];
                a0 = fmaf(g0.x, m, a0); a1 = fmaf(g0.y, m, a1);
                a2 = fmaf(g1.x, m, a2); a3 = fmaf(g1.y, m, a3);
                a4 = fmaf(g2.x, m, a4); a5 = fmaf(g2.y, m, a5);
                a6 = fmaf(g3.x, m, a6); a7 = fmaf(g3.y, m, a7);
            }
        }
        float d = dinv[r];
        float* xr = &Xs[lr * XS + 8 * q];
        const float* bf = &bb[8 * q];
        xr[0] = fmaxf(fmaf(a0, d, bf[0]), 0.f);
        xr[1] = fmaxf(fmaf(a1, d, bf[1]), 0.f);
        xr[2] = fmaxf(fmaf(a2, d, bf[2]), 0.f);
        xr[3] = fmaxf(fmaf(a3, d, bf[3]), 0.f);
        xr[4] = fmaxf(fmaf(a4, d, bf[4]), 0.f);
        xr[5] = fmaxf(fmaf(a5, d, bf[5]), 0.f);
        xr[6] = fmaxf(fmaf(a6, d, bf[6]), 0.f);
        xr[7] = fmaxf(fmaf(a7, d, bf[7]), 0.f);
    }
    __syncthreads();

    // ---- phase 2: Xs[128,48] @ W2[48,32] -> Hh2 (fp16); 2 rows x 8 cols ----
    int tc = tid & 3, tr = tid >> 2;
    int r0l = 2 * tr, c0 = tc * 8;
    float acc[2][8];
#pragma unroll
    for (int rr = 0; rr < 2; ++rr)
#pragma unroll
        for (int j = 0; j < 8; ++j) acc[rr][j] = 0.f;
#pragma unroll 4
    for (int k = 0; k < 48; ++k) {
        float x0 = Xs[r0l * XS + k];
        float x1 = Xs[(r0l + 1) * XS + k];
        float4 wv0 = *(const float4*)&w2[k * 32 + c0];
        float4 wv1 = *(const float4*)&w2[k * 32 + c0 + 4];
        acc[0][0] = fmaf(x0, wv0.x, acc[0][0]); acc[0][1] = fmaf(x0, wv0.y, acc[0][1]);
        acc[0][2] = fmaf(x0, wv0.z, acc[0][2]); acc[0][3] = fmaf(x0, wv0.w, acc[0][3]);
        acc[0][4] = fmaf(x0, wv1.x, acc[0][4]); acc[0][5] = fmaf(x0, wv1.y, acc[0][5]);
        acc[0][6] = fmaf(x0, wv1.z, acc[0][6]); acc[0][7] = fmaf(x0, wv1.w, acc[0][7]);
        acc[1][0] = fmaf(x1, wv0.x, acc[1][0]); acc[1][1] = fmaf(x1, wv0.y, acc[1][1]);
        acc[1][2] = fmaf(x1, wv0.z, acc[1][2]); acc[1][3] = fmaf(x1, wv0.w, acc[1][3]);
        acc[1][4] = fmaf(x1, wv1.x, acc[1][4]); acc[1][5] = fmaf(x1, wv1.y, acc[1][5]);
        acc[1][6] = fmaf(x1, wv1.z, acc[1][6]); acc[1][7] = fmaf(x1, wv1.w, acc[1][7]);
    }
#pragma unroll
    for (int rr = 0; rr < 2; ++rr) {
        int gr = R0 + r0l + rr;
        if (gr >= NN) continue;
        float d = dinv[gr];
        __half2 p0 = __floats2half2_rn(acc[rr][0] * d, acc[rr][1] * d);
        __half2 p1 = __floats2half2_rn(acc[rr][2] * d, acc[rr][3] * d);
        __half2 p2 = __floats2half2_rn(acc[rr][4] * d, acc[rr][5] * d);
        __half2 p3 = __floats2half2_rn(acc[rr][6] * d, acc[rr][7] * d);
        half8 hv; hv.a = p0; hv.b = p1; hv.c = p2; hv.d = p3;
        *(half8*)(Hh2 + (size_t)gr * 32 + c0) = hv;
    }
}

// Layer-2 aggregation: out[i,:] = dinv[i]*(Hh2[i,:] + sum Hh2[src,:]) + b2
// Masked full-width UN-batches. UNCHANGED (Hh2 prescaled by fused48).
template <int NC>
__global__ void k_agg(const __half* __restrict__ Hh, const unsigned int* __restrict__ rowinfo,
                      const int* __restrict__ srcsort, const float* __restrict__ dinv,
                      const float* __restrict__ bias, float* __restrict__ out) {
    constexpr int Q = NC / 8;
    int idx = blockIdx.x * blockDim.x + threadIdx.x;
    if (idx >= NN * Q) return;
    int r = idx / Q, q = idx - r * Q;
    half8 sv = *(const half8*)(Hh + (size_t)r * NC + 8 * q);
    float2 f0 = __half22float2(sv.a), f1 = __half22float2(sv.b);
    float2 f2 = __half22float2(sv.c), f3 = __half22float2(sv.d);
    float a0 = f0.x, a1 = f0.y, a2 = f1.x, a3 = f1.y;
    float a4 = f2.x, a5 = f2.y, a6 = f3.x, a7 = f3.y;
    unsigned int rp = rowinfo[r];
    int e0 = rp >> 10, e1 = e0 + (int)(rp & 1023);
    for (int e = e0; e < e1; e += UN) {
        int ss[UN]; float ms[UN];
#pragma unroll
        for (int u = 0; u < UN; ++u) {
            int ee = e + u;
            bool ok = ee < e1;
            ss[u] = srcsort[ok ? ee : e0];
            ms[u] = ok ? 1.f : 0.f;
        }
        half8 vv[UN];
#pragma unroll
        for (int u = 0; u < UN; ++u)
            vv[u] = *(const half8*)(Hh + (size_t)ss[u] * NC + 8 * q);
#pragma unroll
        for (int u = 0; u < UN; ++u) {
            float2 g0 = __half22float2(vv[u].a), g1 = __half22float2(vv[u].b);
            float2 g2 = __half22float2(vv[u].c), g3 = __half22float2(vv[u].d);
            float m = ms[u];
            a0 = fmaf(g0.x, m, a0); a1 = fmaf(g0.y, m, a1);
            a2 = fmaf(g1.x, m, a2); a3 = fmaf(g1.y, m, a3);
            a4 = fmaf(g2.x, m, a4); a5 = fmaf(g2.y, m, a5);
            a6 = fmaf(g3.x, m, a6); a7 = fmaf(g3.y, m, a7);
        }
    }
    float d = dinv[r];
    const float4* b4 = (const float4*)bias;
    float4 bv0 = b4[2 * q], bv1 = b4[2 * q + 1];
    a0 = fmaf(a0, d, bv0.x); a1 = fmaf(a1, d, bv0.y);
    a2 = fmaf(a2, d, bv0.z); a3 = fmaf(a3, d, bv0.w);
    a4 = fmaf(a4, d, bv1.x); a5 = fmaf(a5, d, bv1.y);
    a6 = fmaf(a6, d, bv1.z); a7 = fmaf(a7, d, bv1.w);
    float4* o4 = (float4*)(out + (size_t)r * NC + 8 * q);
    o4[0] = make_float4(a0, a1, a2, a3);
    o4[1] = make_float4(a4, a5, a6, a7);
}

extern "C" void kernel_launch(void* const* d_in, const int* in_sizes, int n_in,
                              void* d_out, int out_size, void* d_ws, size_t ws_size,
                              hipStream_t stream) {
    const float* x  = (const float*)d_in[0];
    const int*   ei = (const int*)d_in[1];   // [2,NE] int32
    const float* W1 = (const float*)d_in[2];
    const float* b1 = (const float*)d_in[3];
    const float* W2 = (const float*)d_in[4];
    const float* b2 = (const float*)d_in[5];
    float* out = (float*)d_out;

    const int* src = ei;
    const int* dst = ei + NE;

    char* p = (char*)d_ws;
    auto take = [&](size_t elems) { void* q = p; p += ((elems * 4 + 255) & ~255ull); return q; };
    unsigned int* rowinfo = (unsigned int*)take(NN);
    float*        dinv    = (float*)take(NN);
    int*          deg     = (int*)take(NN);
    int*          srcsort = (int*)take((size_t)NBUCK * CAP);   // bucket-padded
    __half*       Hh      = (__half*)take((size_t)NN * 24);    // NN*48 halves
    unsigned int* seg     = (unsigned int*)take((size_t)PART_G * NBUCK);  // 1.2 MB
    int*          runs    = (int*)take((size_t)PART_G * RUNW); // 6.4 MB, dead after bsortgemm
    __half*       Hh2     = (__half*)runs;                     // reuse (NN*32 halves = 6.4 MB)

    const int B = 256;
    // --- partition (coalesced writes) + deg histogram ---
    hipMemsetAsync(deg, 0, NN * sizeof(int), stream);
    k_part<<<PART_G, PART_B, 0, stream>>>(src, dst, runs, seg, deg);
    // --- merged: per-bucket sort (no prescale) + GEMM1 (prescaled via deg) ---
    k_bsortgemm<<<NBUCK + GEMM2_G, 256, 0, stream>>>(runs, seg, srcsort, rowinfo,
                                                     dinv, deg, x, W1, Hh);
    // --- fused: layer-1 aggregation (prescaled Hh) + relu/b1 + GEMM2 ---
    k_fused48<<<GB, 256, 0, stream>>>(Hh, rowinfo, srcsort, dinv, b1, W2, Hh2);
    // --- layer-2 aggregation (+b2) ---
    k_agg<32><<<(NN * 4 + B - 1) / B, B, 0, stream>>>(Hh2, rowinfo, srcsort, dinv, b2, out);
}

// Round 13
// 193.522 us; speedup vs baseline: 1.3013x; 1.3013x over previous
//
#include <hip/hip_runtime.h>
#include <hip/hip_fp16.h>

// GCN 2-layer -- r25 = r23 verbatim (session best, 193.6us). Final config.
// Ledger (complete):
//  r16 (374us): scatter-to-final-slot = 120MB random 64B RMW @0.8TB/s.
//      Random WRITES are the fabric's weak axis. Keep the two-stage sort.
//  r17 (231us): fat k_part blocks -> latency-starved. 391x512xEPT8 proven.
//  r18b (206us): GEMM1 under RMW-bound k_part: zero overlap.
//  r19 (200.5us): per-block LDS sort -> coalesced runs+seg; bsort2 gathers
//      segments (random READS = fast axis, 2.4-2.6TB/s). GEMM1 overlap real.
//  r20 (202.4us): LDS-staged per-edge dinv WORSE; seg transpose ~= wash.
//  r21 (198.8us): Hh prescale folded into bsort2 (partially hidden).
//  r22 (653us): mega-kernel + software grid barriers CATASTROPHIC (768
//      resident slots < 782 blocks -> spin storms). Sync at kernel bounds.
//  r23 (193.6us): r21 minus segt. BEST.
//  r24 (251.8us): deg via global atomicAdd REFUTED -- device-scope atomics
//      to a shared dense array on 8 XCDs are fabric-serialized line RMWs
//      (+50MB WRITE, +27us in k_part). Global atomics ~= random RMW writes.
// Floor accounting (why this is the roofline of this approach):
//  fused48: 96B rows -> exactly 2 lines/row; 8 XCDs x 100k x 128B = 102.4MB
//      compulsory @ 2.55TB/s measured random-line ceiling = 40-43us.
//      Measured 43.5us. AT FLOOR. (Pad/split row layouts all compute >=128B;
//      fp8 blows the 7.7e-3 absmax threshold -- prior session.)
//  agg: 64B aligned rows -> ~71MB compulsory ~= 28us. AT FLOOR.
//  partition: latency-bound at proven geometry; all variants regressed.
//  bsort2: random-read fast axis; transpose wash; prescale placement optimal.
// out = GCNConv(relu(GCNConv(x,W1,b1)), W2, b2); N=100k, E=1.6M, 64->48->32.

#define NN 100000
#define NE 1600000
#define NPB 128                         // nodes per bucket
#define NBUCK ((NN + NPB - 1) / NPB)    // 782
#define PBITS 17                        // src fits in 17 bits
#define PMASK ((1 << PBITS) - 1)
#define CHB 3                           // log2 src chunks
#define CHS 14                          // chunk = src >> 14
#define NKEY (NPB << CHB)               // 1024 sort keys per bucket
#define CAP 4096                        // static slots per bucket (45-sigma)
#define UN 8                            // agg edge-loop unroll (masked batches)
#define PART_B 512
#define EPT 8                           // edges per thread
#define RUNW (PART_B * EPT)             // 4096 edges per partition block run
#define PART_G ((NE + RUNW - 1) / RUNW) // 391
#define GROWS 256                       // rows per GEMM block (512 thr)
#define GEMM_G ((NN + GROWS - 1) / GROWS)                   // 391
#define GB NBUCK                        // fused48 / bsort grid (782)

struct alignas(8)  half4 { __half2 lo, hi; };
struct alignas(16) half8 { __half2 a, b, c, d; };

// Merged launch, 512 threads.
// Blocks [0,PART_G): local counting sort of 4096 edges by bucket in LDS;
//   write contiguous run (coalesced 16KB) + seg word per (blk,bucket):
//   (local_start << 9) | count.
// Blocks [PART_G, PART_G+GEMM_G): GEMM1 Hh = half(X @ W1), UNSCALED
//   (bsort2 rescales in place once dinv is known).
__global__ __launch_bounds__(512) void
k_lsortgemm(const int* __restrict__ src, const int* __restrict__ dst,
            int* __restrict__ runs, unsigned int* __restrict__ seg,
            const float* __restrict__ X, const float* __restrict__ W1,
            __half* __restrict__ Hh) {
    __shared__ int h[NBUCK];          // count -> prefix -> cursor
    __shared__ int tsum[512];
    __shared__ int stage[RUNW];       // 16 KB
    __shared__ float w[64 * 48];      // 12 KB (gemm branch)
    int tid = threadIdx.x;

    if (blockIdx.x < PART_G) {
        for (int i = tid; i < NBUCK; i += PART_B) h[i] = 0;
        __syncthreads();
        int ebase = blockIdx.x * RUNW;
        int pw[EPT], pb[EPT];
#pragma unroll
        for (int k = 0; k < EPT; ++k) {
            int e = ebase + k * PART_B + tid;
            if (e < NE) {
                int d = dst[e];
                pb[k] = d >> 7;
                pw[k] = src[e] | ((d & (NPB - 1)) << PBITS);
                atomicAdd(&h[pb[k]], 1);
            } else pb[k] = -1;
        }
        __syncthreads();
        // scan 782 counters, 2 per thread (tid < 391)
        int c0 = 0, c1 = 0;
        if (tid < NBUCK / 2) { c0 = h[2 * tid]; c1 = h[2 * tid + 1]; }
        int loc = c0 + c1;
        tsum[tid] = (tid < NBUCK / 2) ? loc : 0;
        __syncthreads();
        for (int off = 1; off < 512; off <<= 1) {
            int v = (tid >= off) ? tsum[tid - off] : 0;
            __syncthreads();
            tsum[tid] += v;
            __syncthreads();
        }
        if (tid < NBUCK / 2) {
            int base = tsum[tid] - loc;
            seg[(size_t)blockIdx.x * NBUCK + 2 * tid]     = ((unsigned)base << 9) | (unsigned)c0;
            seg[(size_t)blockIdx.x * NBUCK + 2 * tid + 1] = ((unsigned)(base + c0) << 9) | (unsigned)c1;
            h[2 * tid]     = base;
            h[2 * tid + 1] = base + c0;
        }
        __syncthreads();
#pragma unroll
        for (int k = 0; k < EPT; ++k) {
            if (pb[k] >= 0) {
                int r = atomicAdd(&h[pb[k]], 1);
                stage[r] = pw[k];
            }
        }
        __syncthreads();
#pragma unroll
        for (int k = 0; k < EPT; ++k)
            runs[(size_t)blockIdx.x * RUNW + k * PART_B + tid] = stage[k * PART_B + tid];
        return;
    }

    // ---- GEMM1 (register-tiled, 256 rows/block @512thr, 2x12 per thread) ----
    constexpr int NC = 48, CPT = 12, CG = 4, KF4 = 16;
    int R0 = (blockIdx.x - PART_G) * GROWS;
    for (int i = tid; i < 64 * 48; i += 512) w[i] = W1[i];
    __syncthreads();

    int tc = tid % CG, tr = tid / CG;          // tr in [0,128)
    int r0 = R0 + 2 * tr, r1 = r0 + 1;
    int c0 = tc * CPT;
    bool ok0 = r0 < NN, ok1 = r1 < NN;
    const float4* X4 = (const float4*)X;
    const float4 z4 = make_float4(0.f, 0.f, 0.f, 0.f);

    float acc[2][CPT];
#pragma unroll
    for (int rr = 0; rr < 2; ++rr)
#pragma unroll
        for (int j = 0; j < CPT; ++j) acc[rr][j] = 0.f;

#pragma unroll 2
    for (int k4 = 0; k4 < KF4; ++k4) {
        float4 xa = ok0 ? X4[(size_t)r0 * KF4 + k4] : z4;
        float4 xb = ok1 ? X4[(size_t)r1 * KF4 + k4] : z4;
        float ar[4] = {xa.x, xa.y, xa.z, xa.w};
        float br[4] = {xb.x, xb.y, xb.z, xb.w};
#pragma unroll
        for (int j = 0; j < 4; ++j) {
            float va = ar[j], vb = br[j];
#pragma unroll
            for (int q = 0; q < CPT / 4; ++q) {
                float4 wv = *(const float4*)&w[(4 * k4 + j) * NC + c0 + 4 * q];
                acc[0][q*4+0] = fmaf(va, wv.x, acc[0][q*4+0]);
                acc[0][q*4+1] = fmaf(va, wv.y, acc[0][q*4+1]);
                acc[0][q*4+2] = fmaf(va, wv.z, acc[0][q*4+2]);
                acc[0][q*4+3] = fmaf(va, wv.w, acc[0][q*4+3]);
                acc[1][q*4+0] = fmaf(vb, wv.x, acc[1][q*4+0]);
                acc[1][q*4+1] = fmaf(vb, wv.y, acc[1][q*4+1]);
                acc[1][q*4+2] = fmaf(vb, wv.z, acc[1][q*4+2]);
                acc[1][q*4+3] = fmaf(vb, wv.w, acc[1][q*4+3]);
            }
        }
    }
#pragma unroll
    for (int rr = 0; rr < 2; ++rr) {
        int gr = r0 + rr;
        if (gr >= NN) continue;
#pragma unroll
        for (int q = 0; q < CPT / 4; ++q) {
            __half2 p0 = __floats2half2_rn(acc[rr][q*4+0], acc[rr][q*4+1]);
            __half2 p1 = __floats2half2_rn(acc[rr][q*4+2], acc[rr][q*4+3]);
            half4 hv; hv.lo = p0; hv.hi = p1;
            *(half4*)(Hh + (size_t)gr * NC + c0 + 4 * q) = hv;
        }
    }
}

// Per-bucket sort + Hh prescale (r21 proven). Block b gathers bucket b's
// 391 segments (seg read column-major), counting-sorts into srcsort, emits
// rowinfo/dinv, then rescales its own 128 Hh rows in place (coalesced 12KB
// r/w, partially hidden under the gather latency). Race-free by kernel
// boundaries on both sides.
__global__ __launch_bounds__(256) void
k_bsort2(const int* __restrict__ runs, const unsigned int* __restrict__ seg,
         int* __restrict__ srcsort, unsigned int* __restrict__ rowinfo,
         float* __restrict__ dinv, __half* __restrict__ Hh) {
    __shared__ int stage[CAP];          // 16 KB
    __shared__ int cnt[NKEY];           // 4 KB
    __shared__ int tsum[256];
    __shared__ float sd[NPB];           // per-node dinv for the rescale
    int tid = threadIdx.x, b = blockIdx.x;

    // gather segments: thread t handles partition blocks t and t+256
    unsigned int s0 = (tid < PART_G) ? seg[(size_t)tid * NBUCK + b] : 0u;
    unsigned int s1 = (tid + 256 < PART_G) ? seg[(size_t)(tid + 256) * NBUCK + b] : 0u;
    int l0 = (int)(s0 & 511u), l1 = (int)(s1 & 511u);
    int mylen = l0 + l1;
    tsum[tid] = mylen;
    __syncthreads();
    for (int off = 1; off < 256; off <<= 1) {
        int v = (tid >= off) ? tsum[tid - off] : 0;
        __syncthreads();
        tsum[tid] += v;
        __syncthreads();
    }
    int wbase = tsum[tid] - mylen;
    int sz = tsum[255];
    {
        const int* p = runs + (size_t)tid * RUNW + (s0 >> 9);
        for (int i = 0; i < l0; ++i) stage[wbase + i] = p[i];
        p = runs + (size_t)(tid + 256) * RUNW + (s1 >> 9);
        for (int i = 0; i < l1; ++i) stage[wbase + l0 + i] = p[i];
    }
    for (int i = tid; i < NKEY; i += 256) cnt[i] = 0;
    __syncthreads();

    // key count / scan (proven bsort)
    for (int i = tid; i < sz; i += 256) {
        int w = stage[i];
        int key = ((w >> PBITS) << CHB) | ((w & PMASK) >> CHS);
        atomicAdd(&cnt[key], 1);
    }
    __syncthreads();
    int k0 = tid * 4;
    int c0 = cnt[k0], c1 = cnt[k0 + 1], c2 = cnt[k0 + 2], c3 = cnt[k0 + 3];
    int loc = c0 + c1 + c2 + c3;
    tsum[tid] = loc;
    __syncthreads();
    for (int off = 1; off < 256; off <<= 1) {
        int v = (tid >= off) ? tsum[tid - off] : 0;
        __syncthreads();
        tsum[tid] += v;
        __syncthreads();
    }
    int base = tsum[tid] - loc;
    cnt[k0]     = base;
    cnt[k0 + 1] = base + c0;
    cnt[k0 + 2] = base + c0 + c1;
    cnt[k0 + 3] = base + c0 + c1 + c2;
    __syncthreads();
    int e0 = b * CAP;
    if (tid < NPB) {
        int node = b * NPB + tid;
        int rs = cnt[tid << CHB];
        int re = (tid == NPB - 1) ? sz : cnt[(tid + 1) << CHB];
        float dv = rsqrtf((float)(re - rs + 1));   // +1 self-loop
        sd[tid] = dv;
        if (node < NN) {
            rowinfo[node] = ((unsigned int)(e0 + rs) << 10) | (unsigned int)(re - rs);
            dinv[node] = dv;
        }
    }
    __syncthreads();
    // windowed scatter to srcsort (proven)
    for (int i = tid; i < sz; i += 256) {
        int w = stage[i];
        int key = ((w >> PBITS) << CHB) | ((w & PMASK) >> CHS);
        int p = atomicAdd(&cnt[key], 1);
        srcsort[e0 + p] = w & PMASK;
    }
    // Hh prescale for own bucket: 128 rows x 6 half8 chunks, coalesced.
    for (int t = tid; t < NPB * 6; t += 256) {
        int lr = t / 6, q = t - lr * 6;
        int node = b * NPB + lr;
        if (node >= NN) continue;
        float s = sd[lr];
        half8* hp = (half8*)(Hh + (size_t)node * 48 + 8 * q);
        half8 v = *hp;
        float2 f0 = __half22float2(v.a), f1 = __half22float2(v.b);
        float2 f2 = __half22float2(v.c), f3 = __half22float2(v.d);
        v.a = __floats2half2_rn(f0.x * s, f0.y * s);
        v.b = __floats2half2_rn(f1.x * s, f1.y * s);
        v.c = __floats2half2_rn(f2.x * s, f2.y * s);
        v.d = __floats2half2_rn(f3.x * s, f3.y * s);
        *hp = v;
    }
}

// Fused layer-1 aggregation + relu/b1 + GEMM2 + dinv. 128-row tile, 256 thr.
// EXACT r15 proven form: Hh is prescaled (by bsort2), mask = 1.0.
__global__ __launch_bounds__(256) void
k_fused48(const __half* __restrict__ Hh, const unsigned int* __restrict__ rowinfo,
          const int* __restrict__ srcsort, const float* __restrict__ dinv,
          const float* __restrict__ b1, const float* __restrict__ W2,
          __half* __restrict__ Hh2) {
    constexpr int ROWS = 128, XS = 49;
    __shared__ float Xs[ROWS * XS];      // 25088 B
    __shared__ float w2[48 * 32];        // 6144 B
    __shared__ float bb[48];
    int tid = threadIdx.x;
    int R0 = blockIdx.x * ROWS;
    for (int i = tid; i < 48 * 32; i += 256) w2[i] = W2[i];
    if (tid < 48) bb[tid] = b1[tid];
    __syncthreads();

    // ---- phase 1: aggregate into Xs (3 (row,chunk) items per thread) ----
    for (int t = tid; t < ROWS * 6; t += 256) {
        int lr = t / 6, q = t - lr * 6;
        int r = R0 + lr;
        if (r >= NN) continue;
        half8 sv = *(const half8*)(Hh + (size_t)r * 48 + 8 * q);   // self-loop
        float2 f0 = __half22float2(sv.a), f1 = __half22float2(sv.b);
        float2 f2 = __half22float2(sv.c), f3 = __half22float2(sv.d);
        float a0 = f0.x, a1 = f0.y, a2 = f1.x, a3 = f1.y;
        float a4 = f2.x, a5 = f2.y, a6 = f3.x, a7 = f3.y;
        unsigned int rp = rowinfo[r];
        int e0 = rp >> 10, e1 = e0 + (int)(rp & 1023);
        for (int e = e0; e < e1; e += UN) {
            int ss[UN]; float ms[UN];
#pragma unroll
            for (int u = 0; u < UN; ++u) {
                int ee = e + u;
                bool ok = ee < e1;
                ss[u] = srcsort[ok ? ee : e0];
                ms[u] = ok ? 1.f : 0.f;
            }
            half8 vv[UN];
#pragma unroll
            for (int u = 0; u < UN; ++u)
                vv[u] = *(const half8*)(Hh + (size_t)ss[u] * 48 + 8 * q);
#pragma unroll
            for (int u = 0; u < UN; ++u) {
                float2 g0 = __half22float2(vv[u].a), g1 = __half22float2(vv[u].b);
                float2 g2 = __half22float2(vv[u].c), g3 = __half22float2(vv[u].d);
                float m = ms[u];
                a0 = fmaf(g0.x, m, a0); a1 = fmaf(g0.y, m, a1);
                a2 = fmaf(g1.x, m, a2); a3 = fmaf(g1.y, m, a3);
                a4 = fmaf(g2.x, m, a4); a5 = fmaf(g2.y, m, a5);
                a6 = fmaf(g3.x, m, a6); a7 = fmaf(g3.y, m, a7);
            }
        }
        float d = dinv[r];
        float* xr = &Xs[lr * XS + 8 * q];
        const float* bf = &bb[8 * q];
        xr[0] = fmaxf(fmaf(a0, d, bf[0]), 0.f);
        xr[1] = fmaxf(fmaf(a1, d, bf[1]), 0.f);
        xr[2] = fmaxf(fmaf(a2, d, bf[2]), 0.f);
        xr[3] = fmaxf(fmaf(a3, d, bf[3]), 0.f);
        xr[4] = fmaxf(fmaf(a4, d, bf[4]), 0.f);
        xr[5] = fmaxf(fmaf(a5, d, bf[5]), 0.f);
        xr[6] = fmaxf(fmaf(a6, d, bf[6]), 0.f);
        xr[7] = fmaxf(fmaf(a7, d, bf[7]), 0.f);
    }
    __syncthreads();

    // ---- phase 2: Xs[128,48] @ W2[48,32] -> Hh2 (fp16); 2 rows x 8 cols ----
    int tc = tid & 3, tr = tid >> 2;
    int r0l = 2 * tr, c0 = tc * 8;
    float acc[2][8];
#pragma unroll
    for (int rr = 0; rr < 2; ++rr)
#pragma unroll
        for (int j = 0; j < 8; ++j) acc[rr][j] = 0.f;
#pragma unroll 4
    for (int k = 0; k < 48; ++k) {
        float x0 = Xs[r0l * XS + k];
        float x1 = Xs[(r0l + 1) * XS + k];
        float4 wv0 = *(const float4*)&w2[k * 32 + c0];
        float4 wv1 = *(const float4*)&w2[k * 32 + c0 + 4];
        acc[0][0] = fmaf(x0, wv0.x, acc[0][0]); acc[0][1] = fmaf(x0, wv0.y, acc[0][1]);
        acc[0][2] = fmaf(x0, wv0.z, acc[0][2]); acc[0][3] = fmaf(x0, wv0.w, acc[0][3]);
        acc[0][4] = fmaf(x0, wv1.x, acc[0][4]); acc[0][5] = fmaf(x0, wv1.y, acc[0][5]);
        acc[0][6] = fmaf(x0, wv1.z, acc[0][6]); acc[0][7] = fmaf(x0, wv1.w, acc[0][7]);
        acc[1][0] = fmaf(x1, wv0.x, acc[1][0]); acc[1][1] = fmaf(x1, wv0.y, acc[1][1]);
        acc[1][2] = fmaf(x1, wv0.z, acc[1][2]); acc[1][3] = fmaf(x1, wv0.w, acc[1][3]);
        acc[1][4] = fmaf(x1, wv1.x, acc[1][4]); acc[1][5] = fmaf(x1, wv1.y, acc[1][5]);
        acc[1][6] = fmaf(x1, wv1.z, acc[1][6]); acc[1][7] = fmaf(x1, wv1.w, acc[1][7]);
    }
#pragma unroll
    for (int rr = 0; rr < 2; ++rr) {
        int gr = R0 + r0l + rr;
        if (gr >= NN) continue;
        float d = dinv[gr];
        __half2 p0 = __floats2half2_rn(acc[rr][0] * d, acc[rr][1] * d);
        __half2 p1 = __floats2half2_rn(acc[rr][2] * d, acc[rr][3] * d);
        __half2 p2 = __floats2half2_rn(acc[rr][4] * d, acc[rr][5] * d);
        __half2 p3 = __floats2half2_rn(acc[rr][6] * d, acc[rr][7] * d);
        half8 hv; hv.a = p0; hv.b = p1; hv.c = p2; hv.d = p3;
        *(half8*)(Hh2 + (size_t)gr * 32 + c0) = hv;
    }
}

// Layer-2 aggregation: out[i,:] = dinv[i]*(Hh2[i,:] + sum Hh2[src,:]) + b2
// Masked full-width UN-batches. UNCHANGED (Hh2 prescaled by fused48).
template <int NC>
__global__ void k_agg(const __half* __restrict__ Hh, const unsigned int* __restrict__ rowinfo,
                      const int* __restrict__ srcsort, const float* __restrict__ dinv,
                      const float* __restrict__ bias, float* __restrict__ out) {
    constexpr int Q = NC / 8;
    int idx = blockIdx.x * blockDim.x + threadIdx.x;
    if (idx >= NN * Q) return;
    int r = idx / Q, q = idx - r * Q;
    half8 sv = *(const half8*)(Hh + (size_t)r * NC + 8 * q);
    float2 f0 = __half22float2(sv.a), f1 = __half22float2(sv.b);
    float2 f2 = __half22float2(sv.c), f3 = __half22float2(sv.d);
    float a0 = f0.x, a1 = f0.y, a2 = f1.x, a3 = f1.y;
    float a4 = f2.x, a5 = f2.y, a6 = f3.x, a7 = f3.y;
    unsigned int rp = rowinfo[r];
    int e0 = rp >> 10, e1 = e0 + (int)(rp & 1023);
    for (int e = e0; e < e1; e += UN) {
        int ss[UN]; float ms[UN];
#pragma unroll
        for (int u = 0; u < UN; ++u) {
            int ee = e + u;
            bool ok = ee < e1;
            ss[u] = srcsort[ok ? ee : e0];
            ms[u] = ok ? 1.f : 0.f;
        }
        half8 vv[UN];
#pragma unroll
        for (int u = 0; u < UN; ++u)
            vv[u] = *(const half8*)(Hh + (size_t)ss[u] * NC + 8 * q);
#pragma unroll
        for (int u = 0; u < UN; ++u) {
            float2 g0 = __half22float2(vv[u].a), g1 = __half22float2(vv[u].b);
            float2 g2 = __half22float2(vv[u].c), g3 = __half22float2(vv[u].d);
            float m = ms[u];
            a0 = fmaf(g0.x, m, a0); a1 = fmaf(g0.y, m, a1);
            a2 = fmaf(g1.x, m, a2); a3 = fmaf(g1.y, m, a3);
            a4 = fmaf(g2.x, m, a4); a5 = fmaf(g2.y, m, a5);
            a6 = fmaf(g3.x, m, a6); a7 = fmaf(g3.y, m, a7);
        }
    }
    float d = dinv[r];
    const float4* b4 = (const float4*)bias;
    float4 bv0 = b4[2 * q], bv1 = b4[2 * q + 1];
    a0 = fmaf(a0, d, bv0.x); a1 = fmaf(a1, d, bv0.y);
    a2 = fmaf(a2, d, bv0.z); a3 = fmaf(a3, d, bv0.w);
    a4 = fmaf(a4, d, bv1.x); a5 = fmaf(a5, d, bv1.y);
    a6 = fmaf(a6, d, bv1.z); a7 = fmaf(a7, d, bv1.w);
    float4* o4 = (float4*)(out + (size_t)r * NC + 8 * q);
    o4[0] = make_float4(a0, a1, a2, a3);
    o4[1] = make_float4(a4, a5, a6, a7);
}

extern "C" void kernel_launch(void* const* d_in, const int* in_sizes, int n_in,
                              void* d_out, int out_size, void* d_ws, size_t ws_size,
                              hipStream_t stream) {
    const float* x  = (const float*)d_in[0];
    const int*   ei = (const int*)d_in[1];   // [2,NE] int32
    const float* W1 = (const float*)d_in[2];
    const float* b1 = (const float*)d_in[3];
    const float* W2 = (const float*)d_in[4];
    const float* b2 = (const float*)d_in[5];
    float* out = (float*)d_out;

    const int* src = ei;
    const int* dst = ei + NE;

    char* p = (char*)d_ws;
    auto take = [&](size_t elems) { void* q = p; p += ((elems * 4 + 255) & ~255ull); return q; };
    unsigned int* rowinfo = (unsigned int*)take(NN);
    float*        dinv    = (float*)take(NN);
    int*          srcsort = (int*)take((size_t)NBUCK * CAP);   // bucket-padded
    __half*       Hh      = (__half*)take((size_t)NN * 24);    // NN*48 halves
    unsigned int* seg     = (unsigned int*)take((size_t)PART_G * NBUCK);  // 1.2 MB
    int*          runs    = (int*)take((size_t)PART_G * RUNW); // 6.4 MB, dead after bsort2
    __half*       Hh2     = (__half*)runs;                     // reuse (NN*32 halves = 6.4 MB)

    const int B = 256;
    // --- merged: local-sort partition (all writes coalesced) + GEMM1 ---
    k_lsortgemm<<<PART_G + GEMM_G, PART_B, 0, stream>>>(src, dst, runs, seg, x, W1, Hh);
    // --- per-bucket sort (seg column reads) + in-place Hh prescale ---
    k_bsort2<<<NBUCK, 256, 0, stream>>>(runs, seg, srcsort, rowinfo, dinv, Hh);
    // --- fused: layer-1 aggregation (prescaled Hh) + relu/b1 + GEMM2 ---
    k_fused48<<<GB, 256, 0, stream>>>(Hh, rowinfo, srcsort, dinv, b1, W2, Hh2);
    // --- layer-2 aggregation (+b2) ---
    k_agg<32><<<(NN * 4 + B - 1) / B, B, 0, stream>>>(Hh2, rowinfo, srcsort, dinv, b2, out);
}